// Round 9
// baseline (168.105 us; speedup 1.0000x reference)
//
#include <hip/hip_runtime.h>
#include <hip/hip_bf16.h>
#include <hip/hip_fp8.h>

#define N_NODES 50000
#define N_EDGES 800000
#define HB 3125   // hist/scatter blocks: 800000/256
#define GB1 1563  // gemm1 blocks: ceil(50000/32)
#define NBS 49    // scan blocks: ceil(50000/1024)

static constexpr float SCALE = 0.17677669529663687f; // 1/sqrt(32)

typedef __attribute__((ext_vector_type(8))) short bf16x8;
typedef __attribute__((ext_vector_type(4))) float f32x4;
typedef __attribute__((ext_vector_type(2))) float f32x2;
#define MFMA16 __builtin_amdgcn_mfma_f32_16x16x32_bf16

static __device__ inline unsigned short f2bf(float f) {
    __hip_bfloat16 h = __float2bfloat16(f);
    return __builtin_bit_cast(unsigned short, h);
}
static __device__ inline unsigned char f2fp8(float f) {
    __hip_fp8_e4m3 h(f); // OCP e4m3fn, RNE
    return __builtin_bit_cast(unsigned char, h);
}
static __device__ inline float2 bfpair(unsigned u) {
    return make_float2(__uint_as_float(u << 16),
                       __uint_as_float(u & 0xffff0000u));
}
static __device__ inline float dot8f8(const float* q, uint2 u) {
    f32x2 a = __builtin_amdgcn_cvt_pk_f32_fp8(u.x, false);
    f32x2 b = __builtin_amdgcn_cvt_pk_f32_fp8(u.x, true);
    f32x2 c = __builtin_amdgcn_cvt_pk_f32_fp8(u.y, false);
    f32x2 d = __builtin_amdgcn_cvt_pk_f32_fp8(u.y, true);
    return q[0]*a[0] + q[1]*a[1] + q[2]*b[0] + q[3]*b[1]
         + q[4]*c[0] + q[5]*c[1] + q[6]*d[0] + q[7]*d[1];
}
static __device__ inline float dot8(const float* q, uint4 u) {
    float2 a = bfpair(u.x), b = bfpair(u.y), c = bfpair(u.z), d = bfpair(u.w);
    return q[0]*a.x + q[1]*a.y + q[2]*b.x + q[3]*b.y
         + q[4]*c.x + q[5]*c.y + q[6]*d.x + q[7]*d.y;
}
static __device__ inline void acc8(float* acc, float w, uint4 u) {
    float2 a = bfpair(u.x), b = bfpair(u.y), c = bfpair(u.z), d = bfpair(u.w);
    acc[0] += w*a.x; acc[1] += w*a.y; acc[2] += w*b.x; acc[3] += w*b.y;
    acc[4] += w*c.x; acc[5] += w*c.y; acc[6] += w*d.x; acc[7] += w*d.y;
}
static __device__ inline void unpack8(float* o, uint4 u) {
    float2 a = bfpair(u.x), b = bfpair(u.y), c = bfpair(u.z), d = bfpair(u.w);
    o[0]=a.x; o[1]=a.y; o[2]=b.x; o[3]=b.y; o[4]=c.x; o[5]=c.y; o[6]=d.x; o[7]=d.y;
}
static __device__ inline bf16x8 cvt8(const float* p) {
    float4 f0 = *(const float4*)p;
    float4 f1 = *(const float4*)(p + 4);
    bf16x8 r;
    r[0] = (short)f2bf(f0.x); r[1] = (short)f2bf(f0.y);
    r[2] = (short)f2bf(f0.z); r[3] = (short)f2bf(f0.w);
    r[4] = (short)f2bf(f1.x); r[5] = (short)f2bf(f1.y);
    r[6] = (short)f2bf(f1.z); r[7] = (short)f2bf(f1.w);
    return r;
}

// ---------------- D1: hist (blocks 0..HB) || weight fragments (blocks HB..HB+192) ----------------
// No LDS -> histogram runs at full occupancy.
// Fragment convention (consistent for A and B, so exact HW k-order is irrelevant):
//   lane l, elem j  <->  k = ks*32 + (l>>4)*8 + j ;  col = nt*16 + (l&15)

__global__ __launch_bounds__(256) void k_ph(
    const int* __restrict__ dst, int* __restrict__ cnt, int* __restrict__ rank,
    const float* __restrict__ Wq1, const float* __restrict__ Wk1,
    const float* __restrict__ Wv1, const float* __restrict__ Ws1,
    const float* __restrict__ Wq2, const float* __restrict__ Wk2,
    const float* __restrict__ Wv2, const float* __restrict__ Ws2,
    unsigned short* __restrict__ Wf1, unsigned short* __restrict__ Wf2)
{
    if (blockIdx.x < HB) {
        int e = blockIdx.x * 256 + threadIdx.x; // E exact multiple of 256
        rank[e] = atomicAdd(&cnt[dst[e]], 1);
        return;
    }
    int id = (blockIdx.x - HB) * 256 + threadIdx.x;
    if (id < 32768) {
        int j = id & 7, l = (id >> 3) & 63, ks = (id >> 9) & 1, nt = (id >> 10) & 7, m = (id >> 13) & 3;
        const float* W = (m == 0) ? Wq1 : (m == 1) ? Wk1 : (m == 2) ? Wv1 : Ws1;
        int k = ks * 32 + ((l >> 4) << 3) + j;
        int c = nt * 16 + (l & 15);
        Wf1[id] = f2bf(W[k * 128 + c]);
    } else if (id < 49152) {
        int id2 = id - 32768;
        int j = id2 & 7, l = (id2 >> 3) & 63, ks = (id2 >> 9) & 3, g = (id2 >> 11) & 7;
        int m = g >> 1, t = g & 1;
        const float* W = (m == 0) ? Wq2 : (m == 1) ? Wk2 : (m == 2) ? Wv2 : Ws2;
        int k = ks * 32 + ((l >> 4) << 3) + j;
        int c = t * 16 + (l & 15);
        Wf2[id2] = f2bf(W[k * 32 + c]);
    }
}

// ---------------- D2: GEMM1 (blocks 0..GB1) || scan (blocks GB1..GB1+NBS) ----------------
// GEMM1 (MFMA): x[N,64]f32 (converted in-reg) @ {Wq,Wk,Wv,Ws}[64,128] + b
// outputs: qs1[N][256] bf16 (q 0:128, s 128:256); k8[N][128] fp8-e4m3; v1[N][128] bf16
// Epilogue staged per-16-row-half through 4352B/wave LDS -> full-line coalesced stores.

__global__ __launch_bounds__(256) void k_gs(
    const int* __restrict__ cnt, int* __restrict__ row, int* __restrict__ bsum,
    int* __restrict__ boff, int* __restrict__ ctr,
    const float* __restrict__ x, const unsigned short* __restrict__ Wf1,
    const float* __restrict__ bq, const float* __restrict__ bk,
    const float* __restrict__ bv, const float* __restrict__ bs,
    unsigned short* __restrict__ qs1, unsigned char* __restrict__ k8,
    unsigned short* __restrict__ v1, int n)
{
    __shared__ unsigned char smem[4 * 4352]; // per-wave: bf16 [16][136] or fp8 [16][144]
    if (blockIdx.x >= GB1) {
        // ---- scan half ----
        __shared__ int wsum[4];
        __shared__ int lastBlk;
        int b = blockIdx.x - GB1;
        int t = threadIdx.x;
        int base = b * 1024 + t * 4;
        int v0 = (base + 0 < n) ? cnt[base + 0] : 0;
        int v1i = (base + 1 < n) ? cnt[base + 1] : 0;
        int v2 = (base + 2 < n) ? cnt[base + 2] : 0;
        int v3 = (base + 3 < n) ? cnt[base + 3] : 0;
        int s = v0 + v1i + v2 + v3;
        int lane = t & 63, wid = t >> 6;
        int sc = s;
#pragma unroll
        for (int d = 1; d < 64; d <<= 1) {
            int o = __shfl_up(sc, d);
            if (lane >= d) sc += o;
        }
        if (lane == 63) wsum[wid] = sc;
        __syncthreads();
        int woff = 0;
        for (int w = 0; w < wid; ++w) woff += wsum[w];
        int excl = woff + sc - s;
        if (base + 0 < n) row[base + 0] = excl;
        if (base + 1 < n) row[base + 1] = excl + v0;
        if (base + 2 < n) row[base + 2] = excl + v0 + v1i;
        if (base + 3 < n) row[base + 3] = excl + v0 + v1i + v2;
        if (t == 255) {
            bsum[b] = woff + sc;
            __threadfence();
            lastBlk = (atomicAdd(ctr, 1) == NBS - 1);
        }
        __syncthreads();
        if (lastBlk && t < 64) {
            __threadfence();
            int v = (t < NBS) ? ((volatile int*)bsum)[t] : 0;
            int sc2 = v;
#pragma unroll
            for (int d = 1; d < 64; d <<= 1) {
                int o = __shfl_up(sc2, d);
                if (t >= d) sc2 += o;
            }
            boff[t] = sc2 - v; // exclusive block offset
            if (t == (N_NODES >> 10)) row[N_NODES] = N_EDGES - (sc2 - v);
        }
        return;
    }
    // ---- gemm half ----
    int w = threadIdx.x >> 6;
    int l = threadIdx.x & 63;
    int rb = blockIdx.x * 32;
    int lr = l & 15, lk = l >> 4;
    f32x4 acc[2][8];
#pragma unroll
    for (int mt = 0; mt < 2; ++mt)
#pragma unroll
        for (int nt = 0; nt < 8; ++nt) acc[mt][nt] = (f32x4){0.f, 0.f, 0.f, 0.f};
#pragma unroll
    for (int ks = 0; ks < 2; ++ks) {
        bf16x8 a[2];
#pragma unroll
        for (int mt = 0; mt < 2; ++mt) {
            int r = rb + mt * 16 + lr;
            if (r >= n) r = n - 1;
            a[mt] = cvt8(x + (size_t)r * 64 + ks * 32 + lk * 8);
        }
#pragma unroll
        for (int nt = 0; nt < 8; ++nt) {
            bf16x8 b = *(const bf16x8*)(Wf1 + (size_t)((w * 8 + nt) * 1024 + ks * 512 + l * 8));
            acc[0][nt] = MFMA16(a[0], b, acc[0][nt], 0, 0, 0);
            acc[1][nt] = MFMA16(a[1], b, acc[1][nt], 0, 0, 0);
        }
    }
    const float* bptr = (w == 0) ? bq : (w == 1) ? bk : (w == 2) ? bv : bs;
    unsigned char* my = smem + w * 4352;
#pragma unroll
    for (int mt = 0; mt < 2; ++mt) {
        if (w == 1) { // k -> fp8 rows of 128B
            unsigned char* lb = my; // [16][144]
#pragma unroll
            for (int nt = 0; nt < 8; ++nt) {
                float bias = bptr[nt * 16 + lr];
#pragma unroll
                for (int i = 0; i < 4; ++i)
                    lb[(lk * 4 + i) * 144 + nt * 16 + lr] = f2fp8(acc[mt][nt][i] + bias);
            }
#pragma unroll
            for (int p = 0; p < 4; ++p) {
                int rl = p * 4 + lk;
                int r = rb + mt * 16 + rl;
                if (r < n) {
                    uint2 val = *(const uint2*)(lb + rl * 144 + lr * 8);
                    *(uint2*)(k8 + (size_t)r * 128 + lr * 8) = val;
                }
            }
        } else {
            unsigned short* ls = (unsigned short*)my; // [16][136]
#pragma unroll
            for (int nt = 0; nt < 8; ++nt) {
                float bias = bptr[nt * 16 + lr];
#pragma unroll
                for (int i = 0; i < 4; ++i)
                    ls[(lk * 4 + i) * 136 + nt * 16 + lr] = f2bf(acc[mt][nt][i] + bias);
            }
            unsigned short* outp = (w == 0) ? qs1 : (w == 3) ? qs1 + 128 : v1;
            size_t stride = (w == 2) ? 128 : 256;
#pragma unroll
            for (int p = 0; p < 4; ++p) {
                int rl = p * 4 + lk;
                int r = rb + mt * 16 + rl;
                if (r < n) {
                    uint4 val = *(const uint4*)(ls + rl * 136 + lr * 8);
                    *(uint4*)(outp + (size_t)r * stride + lr * 8) = val;
                }
            }
        }
    }
}

// ---------------- scatter ----------------

__global__ void k_scat(const int* __restrict__ src, const int* __restrict__ dst,
                       const int* __restrict__ row, const int* __restrict__ boff,
                       const int* __restrict__ rank, int* __restrict__ col) {
    int e = blockIdx.x * 256 + threadIdx.x;
    int de = dst[e];
    col[row[de] + boff[de >> 10] + rank[e]] = src[e];
}

// ---------------- GEMM 2 (MFMA): h1b[N,128]bf16 @ {Wq,Wk,Wv,Ws}[128,32] + b ----------------
// LDS-staged epilogue; outputs (bf16): qs2[N][64] (q 0:32, s 32:64); kv2[N][64] (k 0:32, v 32:64)

__global__ __launch_bounds__(256) void k_gemm2m(
    const unsigned short* __restrict__ h1b, const unsigned short* __restrict__ Wf2,
    const float* __restrict__ bq, const float* __restrict__ bk,
    const float* __restrict__ bv, const float* __restrict__ bs,
    unsigned short* __restrict__ qs2, unsigned short* __restrict__ kv2, int n)
{
    __shared__ unsigned short lds[4][32][72]; // 18.4 KB
    int w = threadIdx.x >> 6;
    int l = threadIdx.x & 63;
    int half = w & 1;
    int rb = blockIdx.x * 64 + (w >> 1) * 32;
    int lr = l & 15, lk = l >> 4;
    f32x4 acc[2][4];
#pragma unroll
    for (int mt = 0; mt < 2; ++mt)
#pragma unroll
        for (int nt = 0; nt < 4; ++nt) acc[mt][nt] = (f32x4){0.f, 0.f, 0.f, 0.f};
#pragma unroll
    for (int ks = 0; ks < 4; ++ks) {
        bf16x8 a[2];
#pragma unroll
        for (int mt = 0; mt < 2; ++mt) {
            int r = rb + mt * 16 + lr;
            if (r >= n) r = n - 1;
            a[mt] = *(const bf16x8*)(h1b + (size_t)r * 128 + ks * 32 + lk * 8);
        }
#pragma unroll
        for (int nt = 0; nt < 4; ++nt) {
            int g = half * 4 + nt;
            bf16x8 b = *(const bf16x8*)(Wf2 + (size_t)((g * 4 + ks) * 512 + l * 8));
            acc[0][nt] = MFMA16(a[0], b, acc[0][nt], 0, 0, 0);
            acc[1][nt] = MFMA16(a[1], b, acc[1][nt], 0, 0, 0);
        }
    }
#pragma unroll
    for (int nt = 0; nt < 4; ++nt) {
        int g = half * 4 + nt;
        int mat = g >> 1;
        int c = (g * 16 + lr) & 31;
        const float* bp = (mat == 0) ? bq : (mat == 1) ? bk : (mat == 2) ? bv : bs;
        float bias = bp[c];
#pragma unroll
        for (int mt = 0; mt < 2; ++mt)
#pragma unroll
            for (int i = 0; i < 4; ++i)
                lds[w][mt * 16 + lk * 4 + i][nt * 16 + lr] = f2bf(acc[mt][nt][i] + bias);
    }
    unsigned short* outA = (half == 0) ? qs2 : kv2 + 32; // q : v
    unsigned short* outB = (half == 0) ? kv2 : qs2 + 32; // k : s
    int rl8 = l >> 3, ci = (l & 7) * 4;
#pragma unroll
    for (int p = 0; p < 4; ++p) {
        int rl = p * 8 + rl8;
        int r = rb + rl;
        if (r < n) {
            uint2 va = *(const uint2*)&lds[w][rl][ci];
            *(uint2*)(outA + (size_t)r * 64 + ci) = va;
            uint2 vb = *(const uint2*)&lds[w][rl][32 + ci];
            *(uint2*)(outB + (size_t)r * 64 + ci) = vb;
        }
    }
}

// ---------------- Layer-1 attention aggregate ----------------
// one wave per dst node; lane = slot(0-3)*16 + w(0-15); lane owns channels [w*8, w*8+8).
// 8 edges per iteration. k gathered as fp8 (8B/lane), v as bf16 (16B/lane).

__global__ __launch_bounds__(256) void k_agg1(
    const unsigned short* __restrict__ qs1, const unsigned char* __restrict__ k8,
    const unsigned short* __restrict__ v1,
    const int* __restrict__ row, const int* __restrict__ boff,
    const int* __restrict__ col, uint4* __restrict__ h1b, int n)
{
    int i = blockIdx.x * 4 + (threadIdx.x >> 6);
    if (i >= n) return;
    int lane = threadIdx.x & 63;
    int slot = lane >> 4, w = lane & 15;
    float q[8];
    unpack8(q, *(const uint4*)(qs1 + (size_t)i * 256 + w * 8));
    float acc[8] = {};
    float d = 0.f;
    int s = row[i] + boff[i >> 10];
    int e = row[i + 1] + boff[(i + 1) >> 10];
    for (int t = s; t < e; t += 8) {
        int ta = t + slot, tb = t + 4 + slot;
        bool va = ta < e, vb = tb < e;
        int ja = col[va ? ta : s];
        int jb = col[vb ? tb : s];
        uint2 ka = *(const uint2*)(k8 + (size_t)ja * 128 + w * 8);
        uint2 kb = *(const uint2*)(k8 + (size_t)jb * 128 + w * 8);
        uint4 vA = *(const uint4*)(v1 + (size_t)ja * 128 + w * 8);
        uint4 vB = *(const uint4*)(v1 + (size_t)jb * 128 + w * 8);
        float la = dot8f8(q, ka);
        float lb = dot8f8(q, kb);
        la += __shfl_xor(la, 1);  lb += __shfl_xor(lb, 1);
        la += __shfl_xor(la, 2);  lb += __shfl_xor(lb, 2);
        float wa = va ? __expf(la * SCALE) : 0.f;
        float wb = vb ? __expf(lb * SCALE) : 0.f;
        d += wa + wb;
        acc8(acc, wa, vA);
        acc8(acc, wb, vB);
    }
#pragma unroll
    for (int m = 16; m <= 32; m <<= 1) {
        d += __shfl_xor(d, m);
#pragma unroll
        for (int c = 0; c < 8; ++c) acc[c] += __shfl_xor(acc[c], m);
    }
    if (slot == 0) {
        float inv = (d > 0.f) ? 1.f / d : 0.f;
        float sv[8];
        unpack8(sv, *(const uint4*)(qs1 + (size_t)i * 256 + 128 + w * 8));
        unsigned o[4];
#pragma unroll
        for (int p = 0; p < 4; ++p) {
            float rx = acc[2 * p] * inv + sv[2 * p];
            float ry = acc[2 * p + 1] * inv + sv[2 * p + 1];
            rx = (rx > 0.f) ? rx : expm1f(rx); // ELU
            ry = (ry > 0.f) ? ry : expm1f(ry);
            o[p] = ((unsigned)f2bf(ry) << 16) | (unsigned)f2bf(rx);
        }
        h1b[(size_t)i * 16 + w] = make_uint4(o[0], o[1], o[2], o[3]);
    }
}

// ---------------- Layer-2 attention aggregate ----------------
// one wave per dst node; lane = slot(0-15)*4 + qr(0-3); 16 edges/iteration.

__global__ __launch_bounds__(256) void k_agg2(
    const unsigned short* __restrict__ qs2, const unsigned short* __restrict__ kv2,
    const int* __restrict__ row, const int* __restrict__ boff,
    const int* __restrict__ col, float* __restrict__ out, int n)
{
    int i = blockIdx.x * 4 + (threadIdx.x >> 6);
    if (i >= n) return;
    int lane = threadIdx.x & 63;
    int slot = lane >> 2, qr = lane & 3;
    float q[8];
    unpack8(q, *(const uint4*)(qs2 + (size_t)i * 64 + qr * 8));
    float acc[8] = {};
    float d = 0.f;
    int s = row[i] + boff[i >> 10];
    int e = row[i + 1] + boff[(i + 1) >> 10];
    for (int t = s; t < e; t += 16) {
        int te = t + slot;
        bool va = te < e;
        int j = col[va ? te : s];
        const unsigned short* p = kv2 + (size_t)j * 64;
        uint4 ku = *(const uint4*)(p + qr * 8);
        uint4 vu = *(const uint4*)(p + 32 + qr * 8);
        float lg = dot8(q, ku);
        lg += __shfl_xor(lg, 1);
        lg += __shfl_xor(lg, 2);
        float wv = va ? __expf(lg * SCALE) : 0.f;
        d += wv;
        acc8(acc, wv, vu);
    }
#pragma unroll
    for (int m = 4; m <= 32; m <<= 1) {
        d += __shfl_xor(d, m);
#pragma unroll
        for (int c = 0; c < 8; ++c) acc[c] += __shfl_xor(acc[c], m);
    }
    if (slot == 0) {
        float inv = (d > 0.f) ? 1.f / d : 0.f;
        float sv[8];
        unpack8(sv, *(const uint4*)(qs2 + (size_t)i * 64 + 32 + qr * 8));
        float4 o0, o1;
        o0.x = acc[0] * inv + sv[0];
        o0.y = acc[1] * inv + sv[1];
        o0.z = acc[2] * inv + sv[2];
        o0.w = acc[3] * inv + sv[3];
        o1.x = acc[4] * inv + sv[4];
        o1.y = acc[5] * inv + sv[5];
        o1.z = acc[6] * inv + sv[6];
        o1.w = acc[7] * inv + sv[7];
        *(float4*)&out[(size_t)i * 32 + qr * 8] = o0;
        *(float4*)&out[(size_t)i * 32 + qr * 8 + 4] = o1;
    }
}

// ---------------- launch ----------------

extern "C" void kernel_launch(void* const* d_in, const int* in_sizes, int n_in,
                              void* d_out, int out_size, void* d_ws, size_t ws_size,
                              hipStream_t stream)
{
    const int N = N_NODES, E = N_EDGES;
    const float* x   = (const float*)d_in[0];
    const int* edge  = (const int*)d_in[1];
    const int* src   = edge;       // edge_index[0]
    const int* dst   = edge + E;   // edge_index[1]
    const float* Wq1 = (const float*)d_in[2];  const float* bq1 = (const float*)d_in[3];
    const float* Wk1 = (const float*)d_in[4];  const float* bk1 = (const float*)d_in[5];
    const float* Wv1 = (const float*)d_in[6];  const float* bv1 = (const float*)d_in[7];
    const float* Ws1 = (const float*)d_in[8];  const float* bs1 = (const float*)d_in[9];
    const float* Wq2 = (const float*)d_in[10]; const float* bq2 = (const float*)d_in[11];
    const float* Wk2 = (const float*)d_in[12]; const float* bk2 = (const float*)d_in[13];
    const float* Wv2 = (const float*)d_in[14]; const float* bv2 = (const float*)d_in[15];
    const float* Ws2 = (const float*)d_in[16]; const float* bs2 = (const float*)d_in[17];

    char* ws = (char*)d_ws;
    size_t off = 0;
    auto alloc = [&](size_t bytes) -> void* {
        void* p = ws + off;
        off += (bytes + 255) & ~(size_t)255;
        return p;
    };
    unsigned short* qs1 = (unsigned short*)alloc((size_t)N * 256 * 2); // 25.6 MB
    unsigned char*  k8  = (unsigned char*)alloc((size_t)N * 128);      //  6.4 MB
    unsigned short* v1  = (unsigned short*)alloc((size_t)N * 128 * 2); // 12.8 MB
    unsigned short* h1b = (unsigned short*)alloc((size_t)N * 128 * 2); // 12.8 MB
    unsigned short* qs2 = (unsigned short*)alloc((size_t)N * 64 * 2);  //  6.4 MB
    unsigned short* kv2 = (unsigned short*)alloc((size_t)N * 64 * 2);  //  6.4 MB
    unsigned short* Wf1 = (unsigned short*)alloc(32768 * 2);
    unsigned short* Wf2 = (unsigned short*)alloc(16384 * 2);
    int* row_ptr  = (int*)alloc((size_t)(N + 1) * 4);
    int* cnt      = (int*)alloc((size_t)(N + 64) * 4); // cnt[N] + ctr
    int* ctr      = cnt + N;
    int* rank     = (int*)alloc((size_t)E * 4);
    int* colb     = (int*)alloc((size_t)E * 4);
    int* bsum     = (int*)alloc(64 * 4);
    int* boff     = (int*)alloc(64 * 4);

    hipMemsetAsync(cnt, 0, (size_t)(N + 64) * 4, stream);
    k_ph<<<HB + 192, 256, 0, stream>>>(dst, cnt, rank,
                                       Wq1, Wk1, Wv1, Ws1, Wq2, Wk2, Wv2, Ws2,
                                       Wf1, Wf2);
    k_gs<<<GB1 + NBS, 256, 0, stream>>>(cnt, row_ptr, bsum, boff, ctr,
                                        x, Wf1, bq1, bk1, bv1, bs1, qs1, k8, v1, N);
    k_scat<<<HB, 256, 0, stream>>>(src, dst, row_ptr, boff, rank, colb);
    k_agg1<<<(N + 3) / 4, 256, 0, stream>>>(qs1, k8, v1, row_ptr, boff, colb, (uint4*)h1b, N);
    k_gemm2m<<<(N + 63) / 64, 256, 0, stream>>>(h1b, Wf2, bq2, bk2, bv2, bs2, qs2, kv2, N);
    k_agg2<<<(N + 3) / 4, 256, 0, stream>>>(qs2, kv2, row_ptr, boff, colb, (float*)d_out, N);
}

// Round 10
// 164.672 us; speedup vs baseline: 1.0208x; 1.0208x over previous
//
#include <hip/hip_runtime.h>
#include <hip/hip_bf16.h>
#include <hip/hip_fp8.h>

#define N_NODES 50000
#define N_EDGES 800000
#define HB 3125   // hist/scatter blocks: 800000/256
#define GB1 1563  // gemm1 blocks: ceil(50000/32)
#define NBS 49    // scan blocks: ceil(50000/1024)

static constexpr float SCALE = 0.17677669529663687f; // 1/sqrt(32)

typedef __attribute__((ext_vector_type(8))) short bf16x8;
typedef __attribute__((ext_vector_type(4))) float f32x4;
typedef __attribute__((ext_vector_type(2))) float f32x2;
#define MFMA16 __builtin_amdgcn_mfma_f32_16x16x32_bf16

static __device__ inline unsigned short f2bf(float f) {
    __hip_bfloat16 h = __float2bfloat16(f);
    return __builtin_bit_cast(unsigned short, h);
}
static __device__ inline unsigned char f2fp8(float f) {
    __hip_fp8_e4m3 h(f); // OCP e4m3fn, RNE
    return __builtin_bit_cast(unsigned char, h);
}
static __device__ inline float2 bfpair(unsigned u) {
    return make_float2(__uint_as_float(u << 16),
                       __uint_as_float(u & 0xffff0000u));
}
static __device__ inline float dot8f8(const float* q, uint2 u) {
    f32x2 a = __builtin_amdgcn_cvt_pk_f32_fp8(u.x, false);
    f32x2 b = __builtin_amdgcn_cvt_pk_f32_fp8(u.x, true);
    f32x2 c = __builtin_amdgcn_cvt_pk_f32_fp8(u.y, false);
    f32x2 d = __builtin_amdgcn_cvt_pk_f32_fp8(u.y, true);
    return q[0]*a[0] + q[1]*a[1] + q[2]*b[0] + q[3]*b[1]
         + q[4]*c[0] + q[5]*c[1] + q[6]*d[0] + q[7]*d[1];
}
static __device__ inline void acc8f8(float* acc, float w, uint2 u) {
    f32x2 a = __builtin_amdgcn_cvt_pk_f32_fp8(u.x, false);
    f32x2 b = __builtin_amdgcn_cvt_pk_f32_fp8(u.x, true);
    f32x2 c = __builtin_amdgcn_cvt_pk_f32_fp8(u.y, false);
    f32x2 d = __builtin_amdgcn_cvt_pk_f32_fp8(u.y, true);
    acc[0] += w*a[0]; acc[1] += w*a[1]; acc[2] += w*b[0]; acc[3] += w*b[1];
    acc[4] += w*c[0]; acc[5] += w*c[1]; acc[6] += w*d[0]; acc[7] += w*d[1];
}
static __device__ inline float dot8(const float* q, uint4 u) {
    float2 a = bfpair(u.x), b = bfpair(u.y), c = bfpair(u.z), d = bfpair(u.w);
    return q[0]*a.x + q[1]*a.y + q[2]*b.x + q[3]*b.y
         + q[4]*c.x + q[5]*c.y + q[6]*d.x + q[7]*d.y;
}
static __device__ inline void acc8(float* acc, float w, uint4 u) {
    float2 a = bfpair(u.x), b = bfpair(u.y), c = bfpair(u.z), d = bfpair(u.w);
    acc[0] += w*a.x; acc[1] += w*a.y; acc[2] += w*b.x; acc[3] += w*b.y;
    acc[4] += w*c.x; acc[5] += w*c.y; acc[6] += w*d.x; acc[7] += w*d.y;
}
static __device__ inline void unpack8(float* o, uint4 u) {
    float2 a = bfpair(u.x), b = bfpair(u.y), c = bfpair(u.z), d = bfpair(u.w);
    o[0]=a.x; o[1]=a.y; o[2]=b.x; o[3]=b.y; o[4]=c.x; o[5]=c.y; o[6]=d.x; o[7]=d.y;
}
static __device__ inline bf16x8 cvt8(const float* p) {
    float4 f0 = *(const float4*)p;
    float4 f1 = *(const float4*)(p + 4);
    bf16x8 r;
    r[0] = (short)f2bf(f0.x); r[1] = (short)f2bf(f0.y);
    r[2] = (short)f2bf(f0.z); r[3] = (short)f2bf(f0.w);
    r[4] = (short)f2bf(f1.x); r[5] = (short)f2bf(f1.y);
    r[6] = (short)f2bf(f1.z); r[7] = (short)f2bf(f1.w);
    return r;
}

// ---------------- D1: hist (blocks 0..HB) || weight fragments (blocks HB..HB+192) ----------------
// Fragment convention (consistent for A and B, so exact HW k-order is irrelevant):
//   lane l, elem j  <->  k = ks*32 + (l>>4)*8 + j ;  col = nt*16 + (l&15)

__global__ __launch_bounds__(256) void k_ph(
    const int* __restrict__ dst, int* __restrict__ cnt, int* __restrict__ rank,
    const float* __restrict__ Wq1, const float* __restrict__ Wk1,
    const float* __restrict__ Wv1, const float* __restrict__ Ws1,
    const float* __restrict__ Wq2, const float* __restrict__ Wk2,
    const float* __restrict__ Wv2, const float* __restrict__ Ws2,
    unsigned short* __restrict__ Wf1, unsigned short* __restrict__ Wf2)
{
    if (blockIdx.x < HB) {
        int e = blockIdx.x * 256 + threadIdx.x; // E exact multiple of 256
        rank[e] = atomicAdd(&cnt[dst[e]], 1);
        return;
    }
    int id = (blockIdx.x - HB) * 256 + threadIdx.x;
    if (id < 32768) {
        int j = id & 7, l = (id >> 3) & 63, ks = (id >> 9) & 1, nt = (id >> 10) & 7, m = (id >> 13) & 3;
        const float* W = (m == 0) ? Wq1 : (m == 1) ? Wk1 : (m == 2) ? Wv1 : Ws1;
        int k = ks * 32 + ((l >> 4) << 3) + j;
        int c = nt * 16 + (l & 15);
        Wf1[id] = f2bf(W[k * 128 + c]);
    } else if (id < 49152) {
        int id2 = id - 32768;
        int j = id2 & 7, l = (id2 >> 3) & 63, ks = (id2 >> 9) & 3, g = (id2 >> 11) & 7;
        int m = g >> 1, t = g & 1;
        const float* W = (m == 0) ? Wq2 : (m == 1) ? Wk2 : (m == 2) ? Wv2 : Ws2;
        int k = ks * 32 + ((l >> 4) << 3) + j;
        int c = t * 16 + (l & 15);
        Wf2[id2] = f2bf(W[k * 32 + c]);
    }
}

// ---------------- D2: GEMM1 (blocks 0..GB1) || scan (blocks GB1..GB1+NBS) ----------------
// GEMM1 (MFMA): x[N,64]f32 (converted in-reg) @ {Wq,Wk,Wv,Ws}[64,128] + b
// outputs: qs1[N][256] bf16 (q 0:128, s 128:256); k8[N][128] fp8; v8[N][128] fp8
// Epilogue staged per-16-row-half through 4352B/wave LDS -> full-line coalesced stores.

__global__ __launch_bounds__(256) void k_gs(
    const int* __restrict__ cnt, int* __restrict__ row, int* __restrict__ bsum,
    int* __restrict__ boff, int* __restrict__ ctr,
    const float* __restrict__ x, const unsigned short* __restrict__ Wf1,
    const float* __restrict__ bq, const float* __restrict__ bk,
    const float* __restrict__ bv, const float* __restrict__ bs,
    unsigned short* __restrict__ qs1, unsigned char* __restrict__ k8,
    unsigned char* __restrict__ v8, int n)
{
    __shared__ unsigned char smem[4 * 4352]; // per-wave: bf16 [16][136] or fp8 [16][144]
    if (blockIdx.x >= GB1) {
        // ---- scan half ----
        __shared__ int wsum[4];
        __shared__ int lastBlk;
        int b = blockIdx.x - GB1;
        int t = threadIdx.x;
        int base = b * 1024 + t * 4;
        int v0 = (base + 0 < n) ? cnt[base + 0] : 0;
        int v1i = (base + 1 < n) ? cnt[base + 1] : 0;
        int v2 = (base + 2 < n) ? cnt[base + 2] : 0;
        int v3 = (base + 3 < n) ? cnt[base + 3] : 0;
        int s = v0 + v1i + v2 + v3;
        int lane = t & 63, wid = t >> 6;
        int sc = s;
#pragma unroll
        for (int d = 1; d < 64; d <<= 1) {
            int o = __shfl_up(sc, d);
            if (lane >= d) sc += o;
        }
        if (lane == 63) wsum[wid] = sc;
        __syncthreads();
        int woff = 0;
        for (int w = 0; w < wid; ++w) woff += wsum[w];
        int excl = woff + sc - s;
        if (base + 0 < n) row[base + 0] = excl;
        if (base + 1 < n) row[base + 1] = excl + v0;
        if (base + 2 < n) row[base + 2] = excl + v0 + v1i;
        if (base + 3 < n) row[base + 3] = excl + v0 + v1i + v2;
        if (t == 255) {
            bsum[b] = woff + sc;
            __threadfence();
            lastBlk = (atomicAdd(ctr, 1) == NBS - 1);
        }
        __syncthreads();
        if (lastBlk && t < 64) {
            __threadfence();
            int v = (t < NBS) ? ((volatile int*)bsum)[t] : 0;
            int sc2 = v;
#pragma unroll
            for (int d = 1; d < 64; d <<= 1) {
                int o = __shfl_up(sc2, d);
                if (t >= d) sc2 += o;
            }
            boff[t] = sc2 - v; // exclusive block offset
            if (t == (N_NODES >> 10)) row[N_NODES] = N_EDGES - (sc2 - v);
        }
        return;
    }
    // ---- gemm half ----
    int w = threadIdx.x >> 6;
    int l = threadIdx.x & 63;
    int rb = blockIdx.x * 32;
    int lr = l & 15, lk = l >> 4;
    f32x4 acc[2][8];
#pragma unroll
    for (int mt = 0; mt < 2; ++mt)
#pragma unroll
        for (int nt = 0; nt < 8; ++nt) acc[mt][nt] = (f32x4){0.f, 0.f, 0.f, 0.f};
#pragma unroll
    for (int ks = 0; ks < 2; ++ks) {
        bf16x8 a[2];
#pragma unroll
        for (int mt = 0; mt < 2; ++mt) {
            int r = rb + mt * 16 + lr;
            if (r >= n) r = n - 1;
            a[mt] = cvt8(x + (size_t)r * 64 + ks * 32 + lk * 8);
        }
#pragma unroll
        for (int nt = 0; nt < 8; ++nt) {
            bf16x8 b = *(const bf16x8*)(Wf1 + (size_t)((w * 8 + nt) * 1024 + ks * 512 + l * 8));
            acc[0][nt] = MFMA16(a[0], b, acc[0][nt], 0, 0, 0);
            acc[1][nt] = MFMA16(a[1], b, acc[1][nt], 0, 0, 0);
        }
    }
    const float* bptr = (w == 0) ? bq : (w == 1) ? bk : (w == 2) ? bv : bs;
    unsigned char* my = smem + w * 4352;
#pragma unroll
    for (int mt = 0; mt < 2; ++mt) {
        if (w == 1 || w == 2) { // k,v -> fp8 rows of 128B
            unsigned char* lb = my; // [16][144]
#pragma unroll
            for (int nt = 0; nt < 8; ++nt) {
                float bias = bptr[nt * 16 + lr];
#pragma unroll
                for (int i = 0; i < 4; ++i)
                    lb[(lk * 4 + i) * 144 + nt * 16 + lr] = f2fp8(acc[mt][nt][i] + bias);
            }
            unsigned char* outp = (w == 1) ? k8 : v8;
#pragma unroll
            for (int p = 0; p < 4; ++p) {
                int rl = p * 4 + lk;
                int r = rb + mt * 16 + rl;
                if (r < n) {
                    uint2 val = *(const uint2*)(lb + rl * 144 + lr * 8);
                    *(uint2*)(outp + (size_t)r * 128 + lr * 8) = val;
                }
            }
        } else {
            unsigned short* ls = (unsigned short*)my; // [16][136]
#pragma unroll
            for (int nt = 0; nt < 8; ++nt) {
                float bias = bptr[nt * 16 + lr];
#pragma unroll
                for (int i = 0; i < 4; ++i)
                    ls[(lk * 4 + i) * 136 + nt * 16 + lr] = f2bf(acc[mt][nt][i] + bias);
            }
            unsigned short* outp = (w == 0) ? qs1 : qs1 + 128;
#pragma unroll
            for (int p = 0; p < 4; ++p) {
                int rl = p * 4 + lk;
                int r = rb + mt * 16 + rl;
                if (r < n) {
                    uint4 val = *(const uint4*)(ls + rl * 136 + lr * 8);
                    *(uint4*)(outp + (size_t)r * 256 + lr * 8) = val;
                }
            }
        }
    }
}

// ---------------- scatter ----------------

__global__ void k_scat(const int* __restrict__ src, const int* __restrict__ dst,
                       const int* __restrict__ row, const int* __restrict__ boff,
                       const int* __restrict__ rank, int* __restrict__ col) {
    int e = blockIdx.x * 256 + threadIdx.x;
    int de = dst[e];
    col[row[de] + boff[de >> 10] + rank[e]] = src[e];
}

// ---------------- GEMM 2 (MFMA): h1b[N,128]bf16 @ {Wq,Wk,Wv,Ws}[128,32] + b ----------------
// LDS-staged epilogue; outputs (bf16): qs2[N][64] (q 0:32, s 32:64); kv2[N][64] (k 0:32, v 32:64)

__global__ __launch_bounds__(256) void k_gemm2m(
    const unsigned short* __restrict__ h1b, const unsigned short* __restrict__ Wf2,
    const float* __restrict__ bq, const float* __restrict__ bk,
    const float* __restrict__ bv, const float* __restrict__ bs,
    unsigned short* __restrict__ qs2, unsigned short* __restrict__ kv2, int n)
{
    __shared__ unsigned short lds[4][32][72]; // 18.4 KB
    int w = threadIdx.x >> 6;
    int l = threadIdx.x & 63;
    int half = w & 1;
    int rb = blockIdx.x * 64 + (w >> 1) * 32;
    int lr = l & 15, lk = l >> 4;
    f32x4 acc[2][4];
#pragma unroll
    for (int mt = 0; mt < 2; ++mt)
#pragma unroll
        for (int nt = 0; nt < 4; ++nt) acc[mt][nt] = (f32x4){0.f, 0.f, 0.f, 0.f};
#pragma unroll
    for (int ks = 0; ks < 4; ++ks) {
        bf16x8 a[2];
#pragma unroll
        for (int mt = 0; mt < 2; ++mt) {
            int r = rb + mt * 16 + lr;
            if (r >= n) r = n - 1;
            a[mt] = *(const bf16x8*)(h1b + (size_t)r * 128 + ks * 32 + lk * 8);
        }
#pragma unroll
        for (int nt = 0; nt < 4; ++nt) {
            int g = half * 4 + nt;
            bf16x8 b = *(const bf16x8*)(Wf2 + (size_t)((g * 4 + ks) * 512 + l * 8));
            acc[0][nt] = MFMA16(a[0], b, acc[0][nt], 0, 0, 0);
            acc[1][nt] = MFMA16(a[1], b, acc[1][nt], 0, 0, 0);
        }
    }
#pragma unroll
    for (int nt = 0; nt < 4; ++nt) {
        int g = half * 4 + nt;
        int mat = g >> 1;
        int c = (g * 16 + lr) & 31;
        const float* bp = (mat == 0) ? bq : (mat == 1) ? bk : (mat == 2) ? bv : bs;
        float bias = bp[c];
#pragma unroll
        for (int mt = 0; mt < 2; ++mt)
#pragma unroll
            for (int i = 0; i < 4; ++i)
                lds[w][mt * 16 + lk * 4 + i][nt * 16 + lr] = f2bf(acc[mt][nt][i] + bias);
    }
    unsigned short* outA = (half == 0) ? qs2 : kv2 + 32; // q : v
    unsigned short* outB = (half == 0) ? kv2 : qs2 + 32; // k : s
    int rl8 = l >> 3, ci = (l & 7) * 4;
#pragma unroll
    for (int p = 0; p < 4; ++p) {
        int rl = p * 8 + rl8;
        int r = rb + rl;
        if (r < n) {
            uint2 va = *(const uint2*)&lds[w][rl][ci];
            *(uint2*)(outA + (size_t)r * 64 + ci) = va;
            uint2 vb = *(const uint2*)&lds[w][rl][32 + ci];
            *(uint2*)(outB + (size_t)r * 64 + ci) = vb;
        }
    }
}

// ---------------- Layer-1 attention aggregate ----------------
// one wave per dst node; lane = slot(0-3)*16 + w(0-15); lane owns channels [w*8, w*8+8).
// 8 edges per iteration. k AND v gathered as fp8 (8B/lane each).

__global__ __launch_bounds__(256) void k_agg1(
    const unsigned short* __restrict__ qs1, const unsigned char* __restrict__ k8,
    const unsigned char* __restrict__ v8,
    const int* __restrict__ row, const int* __restrict__ boff,
    const int* __restrict__ col, uint4* __restrict__ h1b, int n)
{
    int i = blockIdx.x * 4 + (threadIdx.x >> 6);
    if (i >= n) return;
    int lane = threadIdx.x & 63;
    int slot = lane >> 4, w = lane & 15;
    float q[8];
    unpack8(q, *(const uint4*)(qs1 + (size_t)i * 256 + w * 8));
    float acc[8] = {};
    float d = 0.f;
    int s = row[i] + boff[i >> 10];
    int e = row[i + 1] + boff[(i + 1) >> 10];
    for (int t = s; t < e; t += 8) {
        int ta = t + slot, tb = t + 4 + slot;
        bool va = ta < e, vb = tb < e;
        int ja = col[va ? ta : s];
        int jb = col[vb ? tb : s];
        uint2 ka = *(const uint2*)(k8 + (size_t)ja * 128 + w * 8);
        uint2 kb = *(const uint2*)(k8 + (size_t)jb * 128 + w * 8);
        uint2 vA = *(const uint2*)(v8 + (size_t)ja * 128 + w * 8);
        uint2 vB = *(const uint2*)(v8 + (size_t)jb * 128 + w * 8);
        float la = dot8f8(q, ka);
        float lb = dot8f8(q, kb);
        la += __shfl_xor(la, 1);  lb += __shfl_xor(lb, 1);
        la += __shfl_xor(la, 2);  lb += __shfl_xor(lb, 2);
        float wa = va ? __expf(la * SCALE) : 0.f;
        float wb = vb ? __expf(lb * SCALE) : 0.f;
        d += wa + wb;
        acc8f8(acc, wa, vA);
        acc8f8(acc, wb, vB);
    }
#pragma unroll
    for (int m = 16; m <= 32; m <<= 1) {
        d += __shfl_xor(d, m);
#pragma unroll
        for (int c = 0; c < 8; ++c) acc[c] += __shfl_xor(acc[c], m);
    }
    if (slot == 0) {
        float inv = (d > 0.f) ? 1.f / d : 0.f;
        float sv[8];
        unpack8(sv, *(const uint4*)(qs1 + (size_t)i * 256 + 128 + w * 8));
        unsigned o[4];
#pragma unroll
        for (int p = 0; p < 4; ++p) {
            float rx = acc[2 * p] * inv + sv[2 * p];
            float ry = acc[2 * p + 1] * inv + sv[2 * p + 1];
            rx = (rx > 0.f) ? rx : expm1f(rx); // ELU
            ry = (ry > 0.f) ? ry : expm1f(ry);
            o[p] = ((unsigned)f2bf(ry) << 16) | (unsigned)f2bf(rx);
        }
        h1b[(size_t)i * 16 + w] = make_uint4(o[0], o[1], o[2], o[3]);
    }
}

// ---------------- Layer-2 attention aggregate ----------------
// one wave per dst node; lane = slot(0-15)*4 + qr(0-3); 16 edges/iteration.

__global__ __launch_bounds__(256) void k_agg2(
    const unsigned short* __restrict__ qs2, const unsigned short* __restrict__ kv2,
    const int* __restrict__ row, const int* __restrict__ boff,
    const int* __restrict__ col, float* __restrict__ out, int n)
{
    int i = blockIdx.x * 4 + (threadIdx.x >> 6);
    if (i >= n) return;
    int lane = threadIdx.x & 63;
    int slot = lane >> 2, qr = lane & 3;
    float q[8];
    unpack8(q, *(const uint4*)(qs2 + (size_t)i * 64 + qr * 8));
    float acc[8] = {};
    float d = 0.f;
    int s = row[i] + boff[i >> 10];
    int e = row[i + 1] + boff[(i + 1) >> 10];
    for (int t = s; t < e; t += 16) {
        int te = t + slot;
        bool va = te < e;
        int j = col[va ? te : s];
        const unsigned short* p = kv2 + (size_t)j * 64;
        uint4 ku = *(const uint4*)(p + qr * 8);
        uint4 vu = *(const uint4*)(p + 32 + qr * 8);
        float lg = dot8(q, ku);
        lg += __shfl_xor(lg, 1);
        lg += __shfl_xor(lg, 2);
        float wv = va ? __expf(lg * SCALE) : 0.f;
        d += wv;
        acc8(acc, wv, vu);
    }
#pragma unroll
    for (int m = 4; m <= 32; m <<= 1) {
        d += __shfl_xor(d, m);
#pragma unroll
        for (int c = 0; c < 8; ++c) acc[c] += __shfl_xor(acc[c], m);
    }
    if (slot == 0) {
        float inv = (d > 0.f) ? 1.f / d : 0.f;
        float sv[8];
        unpack8(sv, *(const uint4*)(qs2 + (size_t)i * 64 + 32 + qr * 8));
        float4 o0, o1;
        o0.x = acc[0] * inv + sv[0];
        o0.y = acc[1] * inv + sv[1];
        o0.z = acc[2] * inv + sv[2];
        o0.w = acc[3] * inv + sv[3];
        o1.x = acc[4] * inv + sv[4];
        o1.y = acc[5] * inv + sv[5];
        o1.z = acc[6] * inv + sv[6];
        o1.w = acc[7] * inv + sv[7];
        *(float4*)&out[(size_t)i * 32 + qr * 8] = o0;
        *(float4*)&out[(size_t)i * 32 + qr * 8 + 4] = o1;
    }
}

// ---------------- launch ----------------

extern "C" void kernel_launch(void* const* d_in, const int* in_sizes, int n_in,
                              void* d_out, int out_size, void* d_ws, size_t ws_size,
                              hipStream_t stream)
{
    const int N = N_NODES, E = N_EDGES;
    const float* x   = (const float*)d_in[0];
    const int* edge  = (const int*)d_in[1];
    const int* src   = edge;       // edge_index[0]
    const int* dst   = edge + E;   // edge_index[1]
    const float* Wq1 = (const float*)d_in[2];  const float* bq1 = (const float*)d_in[3];
    const float* Wk1 = (const float*)d_in[4];  const float* bk1 = (const float*)d_in[5];
    const float* Wv1 = (const float*)d_in[6];  const float* bv1 = (const float*)d_in[7];
    const float* Ws1 = (const float*)d_in[8];  const float* bs1 = (const float*)d_in[9];
    const float* Wq2 = (const float*)d_in[10]; const float* bq2 = (const float*)d_in[11];
    const float* Wk2 = (const float*)d_in[12]; const float* bk2 = (const float*)d_in[13];
    const float* Wv2 = (const float*)d_in[14]; const float* bv2 = (const float*)d_in[15];
    const float* Ws2 = (const float*)d_in[16]; const float* bs2 = (const float*)d_in[17];

    char* ws = (char*)d_ws;
    size_t off = 0;
    auto alloc = [&](size_t bytes) -> void* {
        void* p = ws + off;
        off += (bytes + 255) & ~(size_t)255;
        return p;
    };
    unsigned short* qs1 = (unsigned short*)alloc((size_t)N * 256 * 2); // 25.6 MB
    unsigned char*  k8  = (unsigned char*)alloc((size_t)N * 128);      //  6.4 MB
    unsigned char*  v8  = (unsigned char*)alloc((size_t)N * 128);      //  6.4 MB
    unsigned short* h1b = (unsigned short*)alloc((size_t)N * 128 * 2); // 12.8 MB
    unsigned short* qs2 = (unsigned short*)alloc((size_t)N * 64 * 2);  //  6.4 MB
    unsigned short* kv2 = (unsigned short*)alloc((size_t)N * 64 * 2);  //  6.4 MB
    unsigned short* Wf1 = (unsigned short*)alloc(32768 * 2);
    unsigned short* Wf2 = (unsigned short*)alloc(16384 * 2);
    int* row_ptr  = (int*)alloc((size_t)(N + 1) * 4);
    int* cnt      = (int*)alloc((size_t)(N + 64) * 4); // cnt[N] + ctr
    int* ctr      = cnt + N;
    int* rank     = (int*)alloc((size_t)E * 4);
    int* colb     = (int*)alloc((size_t)E * 4);
    int* bsum     = (int*)alloc(64 * 4);
    int* boff     = (int*)alloc(64 * 4);

    hipMemsetAsync(cnt, 0, (size_t)(N + 64) * 4, stream);
    k_ph<<<HB + 192, 256, 0, stream>>>(dst, cnt, rank,
                                       Wq1, Wk1, Wv1, Ws1, Wq2, Wk2, Wv2, Ws2,
                                       Wf1, Wf2);
    k_gs<<<GB1 + NBS, 256, 0, stream>>>(cnt, row_ptr, bsum, boff, ctr,
                                        x, Wf1, bq1, bk1, bv1, bs1, qs1, k8, v8, N);
    k_scat<<<HB, 256, 0, stream>>>(src, dst, row_ptr, boff, rank, colb);
    k_agg1<<<(N + 3) / 4, 256, 0, stream>>>(qs1, k8, v8, row_ptr, boff, colb, (uint4*)h1b, N);
    k_gemm2m<<<(N + 63) / 64, 256, 0, stream>>>(h1b, Wf2, bq2, bk2, bv2, bs2, qs2, kv2, N);
    k_agg2<<<(N + 3) / 4, 256, 0, stream>>>(qs2, kv2, row_ptr, boff, colb, (float*)d_out, N);
}

// Round 11
// 163.785 us; speedup vs baseline: 1.0264x; 1.0054x over previous
//
#include <hip/hip_runtime.h>
#include <hip/hip_bf16.h>
#include <hip/hip_fp8.h>

#define N_NODES 50000
#define N_EDGES 800000
#define HB 3125   // hist/scatter blocks: 800000/256
#define GB1 1563  // gemm1 blocks: ceil(50000/32)
#define NBS 49    // scan blocks: ceil(50000/1024)

static constexpr float SCALE = 0.17677669529663687f; // 1/sqrt(32)

typedef __attribute__((ext_vector_type(8))) short bf16x8;
typedef __attribute__((ext_vector_type(4))) float f32x4;
typedef __attribute__((ext_vector_type(2))) float f32x2;
#define MFMA16 __builtin_amdgcn_mfma_f32_16x16x32_bf16
#define CVT8 __builtin_amdgcn_cvt_pk_f32_fp8

static __device__ inline unsigned short f2bf(float f) {
    __hip_bfloat16 h = __float2bfloat16(f);
    return __builtin_bit_cast(unsigned short, h);
}
static __device__ inline unsigned char f2fp8(float f) {
    __hip_fp8_e4m3 h(f); // OCP e4m3fn, RNE
    return __builtin_bit_cast(unsigned char, h);
}
// packed pair of bf16 (one u32) -> f32x2
static __device__ inline f32x2 bfp2(unsigned u) {
    f32x2 r;
    r[0] = __uint_as_float(u << 16);
    r[1] = __uint_as_float(u & 0xffff0000u);
    return r;
}
static __device__ inline bf16x8 cvt8(const float* p) {
    float4 f0 = *(const float4*)p;
    float4 f1 = *(const float4*)(p + 4);
    bf16x8 r;
    r[0] = (short)f2bf(f0.x); r[1] = (short)f2bf(f0.y);
    r[2] = (short)f2bf(f0.z); r[3] = (short)f2bf(f0.w);
    r[4] = (short)f2bf(f1.x); r[5] = (short)f2bf(f1.y);
    r[6] = (short)f2bf(f1.z); r[7] = (short)f2bf(f1.w);
    return r;
}

// ---------------- D1: hist (blocks 0..HB) || weight fragments (blocks HB..HB+192) ----------------
// Fragment convention (consistent for A and B, so exact HW k-order is irrelevant):
//   lane l, elem j  <->  k = ks*32 + (l>>4)*8 + j ;  col = nt*16 + (l&15)

__global__ __launch_bounds__(256) void k_ph(
    const int* __restrict__ dst, int* __restrict__ cnt, int* __restrict__ rank,
    const float* __restrict__ Wq1, const float* __restrict__ Wk1,
    const float* __restrict__ Wv1, const float* __restrict__ Ws1,
    const float* __restrict__ Wq2, const float* __restrict__ Wk2,
    const float* __restrict__ Wv2, const float* __restrict__ Ws2,
    unsigned short* __restrict__ Wf1, unsigned short* __restrict__ Wf2)
{
    if (blockIdx.x < HB) {
        int e = blockIdx.x * 256 + threadIdx.x; // E exact multiple of 256
        rank[e] = atomicAdd(&cnt[dst[e]], 1);
        return;
    }
    int id = (blockIdx.x - HB) * 256 + threadIdx.x;
    if (id < 32768) {
        int j = id & 7, l = (id >> 3) & 63, ks = (id >> 9) & 1, nt = (id >> 10) & 7, m = (id >> 13) & 3;
        const float* W = (m == 0) ? Wq1 : (m == 1) ? Wk1 : (m == 2) ? Wv1 : Ws1;
        int k = ks * 32 + ((l >> 4) << 3) + j;
        int c = nt * 16 + (l & 15);
        Wf1[id] = f2bf(W[k * 128 + c]);
    } else if (id < 49152) {
        int id2 = id - 32768;
        int j = id2 & 7, l = (id2 >> 3) & 63, ks = (id2 >> 9) & 3, g = (id2 >> 11) & 7;
        int m = g >> 1, t = g & 1;
        const float* W = (m == 0) ? Wq2 : (m == 1) ? Wk2 : (m == 2) ? Wv2 : Ws2;
        int k = ks * 32 + ((l >> 4) << 3) + j;
        int c = t * 16 + (l & 15);
        Wf2[id2] = f2bf(W[k * 32 + c]);
    }
}

// ---------------- D2: GEMM1 (blocks 0..GB1) || scan (blocks GB1..GB1+NBS) ----------------
// GEMM1 (MFMA): x[N,64]f32 (converted in-reg) @ {Wq,Wk,Wv,Ws}[64,128] + b
// outputs: qs1[N][256] bf16 (q 0:128, s 128:256);
//          kv8[N][256 bytes] fp8 interleaved: group w (0..15): k ch w*8..+8 at byte w*16, v at w*16+8.
// Epilogue staged per-16-row-half through 4352B/wave LDS -> coalesced stores
// (k-wave and v-wave cover complementary 8B halves of each line; L2 merges).

__global__ __launch_bounds__(256) void k_gs(
    const int* __restrict__ cnt, int* __restrict__ row, int* __restrict__ bsum,
    int* __restrict__ boff, int* __restrict__ ctr,
    const float* __restrict__ x, const unsigned short* __restrict__ Wf1,
    const float* __restrict__ bq, const float* __restrict__ bk,
    const float* __restrict__ bv, const float* __restrict__ bs,
    unsigned short* __restrict__ qs1, unsigned char* __restrict__ kv8, int n)
{
    __shared__ unsigned char smem[4 * 4352]; // per-wave: bf16 [16][136] or fp8 [16][144]
    if (blockIdx.x >= GB1) {
        // ---- scan half ----
        __shared__ int wsum[4];
        __shared__ int lastBlk;
        int b = blockIdx.x - GB1;
        int t = threadIdx.x;
        int base = b * 1024 + t * 4;
        int v0 = (base + 0 < n) ? cnt[base + 0] : 0;
        int v1i = (base + 1 < n) ? cnt[base + 1] : 0;
        int v2 = (base + 2 < n) ? cnt[base + 2] : 0;
        int v3 = (base + 3 < n) ? cnt[base + 3] : 0;
        int s = v0 + v1i + v2 + v3;
        int lane = t & 63, wid = t >> 6;
        int sc = s;
#pragma unroll
        for (int d = 1; d < 64; d <<= 1) {
            int o = __shfl_up(sc, d);
            if (lane >= d) sc += o;
        }
        if (lane == 63) wsum[wid] = sc;
        __syncthreads();
        int woff = 0;
        for (int w = 0; w < wid; ++w) woff += wsum[w];
        int excl = woff + sc - s;
        if (base + 0 < n) row[base + 0] = excl;
        if (base + 1 < n) row[base + 1] = excl + v0;
        if (base + 2 < n) row[base + 2] = excl + v0 + v1i;
        if (base + 3 < n) row[base + 3] = excl + v0 + v1i + v2;
        if (t == 255) {
            bsum[b] = woff + sc;
            __threadfence();
            lastBlk = (atomicAdd(ctr, 1) == NBS - 1);
        }
        __syncthreads();
        if (lastBlk && t < 64) {
            __threadfence();
            int v = (t < NBS) ? ((volatile int*)bsum)[t] : 0;
            int sc2 = v;
#pragma unroll
            for (int d = 1; d < 64; d <<= 1) {
                int o = __shfl_up(sc2, d);
                if (t >= d) sc2 += o;
            }
            boff[t] = sc2 - v; // exclusive block offset
            if (t == (N_NODES >> 10)) row[N_NODES] = N_EDGES - (sc2 - v);
        }
        return;
    }
    // ---- gemm half ----
    int w = threadIdx.x >> 6;
    int l = threadIdx.x & 63;
    int rb = blockIdx.x * 32;
    int lr = l & 15, lk = l >> 4;
    f32x4 acc[2][8];
#pragma unroll
    for (int mt = 0; mt < 2; ++mt)
#pragma unroll
        for (int nt = 0; nt < 8; ++nt) acc[mt][nt] = (f32x4){0.f, 0.f, 0.f, 0.f};
#pragma unroll
    for (int ks = 0; ks < 2; ++ks) {
        bf16x8 a[2];
#pragma unroll
        for (int mt = 0; mt < 2; ++mt) {
            int r = rb + mt * 16 + lr;
            if (r >= n) r = n - 1;
            a[mt] = cvt8(x + (size_t)r * 64 + ks * 32 + lk * 8);
        }
#pragma unroll
        for (int nt = 0; nt < 8; ++nt) {
            bf16x8 b = *(const bf16x8*)(Wf1 + (size_t)((w * 8 + nt) * 1024 + ks * 512 + l * 8));
            acc[0][nt] = MFMA16(a[0], b, acc[0][nt], 0, 0, 0);
            acc[1][nt] = MFMA16(a[1], b, acc[1][nt], 0, 0, 0);
        }
    }
    const float* bptr = (w == 0) ? bq : (w == 1) ? bk : (w == 2) ? bv : bs;
    unsigned char* my = smem + w * 4352;
#pragma unroll
    for (int mt = 0; mt < 2; ++mt) {
        if (w == 1 || w == 2) { // k,v -> fp8 into interleaved kv8
            unsigned char* lb = my; // [16][144]
#pragma unroll
            for (int nt = 0; nt < 8; ++nt) {
                float bias = bptr[nt * 16 + lr];
#pragma unroll
                for (int i = 0; i < 4; ++i)
                    lb[(lk * 4 + i) * 144 + nt * 16 + lr] = f2fp8(acc[mt][nt][i] + bias);
            }
            int voff = (w == 2) ? 8 : 0; // v occupies the upper 8B of each 16B group
#pragma unroll
            for (int p = 0; p < 4; ++p) {
                int rl = p * 4 + lk;
                int r = rb + mt * 16 + rl;
                if (r < n) {
                    uint2 val = *(const uint2*)(lb + rl * 144 + lr * 8);
                    *(uint2*)(kv8 + (size_t)r * 256 + lr * 16 + voff) = val;
                }
            }
        } else {
            unsigned short* ls = (unsigned short*)my; // [16][136]
#pragma unroll
            for (int nt = 0; nt < 8; ++nt) {
                float bias = bptr[nt * 16 + lr];
#pragma unroll
                for (int i = 0; i < 4; ++i)
                    ls[(lk * 4 + i) * 136 + nt * 16 + lr] = f2bf(acc[mt][nt][i] + bias);
            }
            unsigned short* outp = (w == 0) ? qs1 : qs1 + 128;
#pragma unroll
            for (int p = 0; p < 4; ++p) {
                int rl = p * 4 + lk;
                int r = rb + mt * 16 + rl;
                if (r < n) {
                    uint4 val = *(const uint4*)(ls + rl * 136 + lr * 8);
                    *(uint4*)(outp + (size_t)r * 256 + lr * 8) = val;
                }
            }
        }
    }
}

// ---------------- scatter ----------------

__global__ void k_scat(const int* __restrict__ src, const int* __restrict__ dst,
                       const int* __restrict__ row, const int* __restrict__ boff,
                       const int* __restrict__ rank, int* __restrict__ col) {
    int e = blockIdx.x * 256 + threadIdx.x;
    int de = dst[e];
    col[row[de] + boff[de >> 10] + rank[e]] = src[e];
}

// ---------------- GEMM 2 (MFMA): h1b[N,128]bf16 @ {Wq,Wk,Wv,Ws}[128,32] + b ----------------
// LDS-staged epilogue; outputs (bf16): qs2[N][64] (q 0:32, s 32:64); kv2[N][64] (k 0:32, v 32:64)

__global__ __launch_bounds__(256) void k_gemm2m(
    const unsigned short* __restrict__ h1b, const unsigned short* __restrict__ Wf2,
    const float* __restrict__ bq, const float* __restrict__ bk,
    const float* __restrict__ bv, const float* __restrict__ bs,
    unsigned short* __restrict__ qs2, unsigned short* __restrict__ kv2, int n)
{
    __shared__ unsigned short lds[4][32][72]; // 18.4 KB
    int w = threadIdx.x >> 6;
    int l = threadIdx.x & 63;
    int half = w & 1;
    int rb = blockIdx.x * 64 + (w >> 1) * 32;
    int lr = l & 15, lk = l >> 4;
    f32x4 acc[2][4];
#pragma unroll
    for (int mt = 0; mt < 2; ++mt)
#pragma unroll
        for (int nt = 0; nt < 4; ++nt) acc[mt][nt] = (f32x4){0.f, 0.f, 0.f, 0.f};
#pragma unroll
    for (int ks = 0; ks < 4; ++ks) {
        bf16x8 a[2];
#pragma unroll
        for (int mt = 0; mt < 2; ++mt) {
            int r = rb + mt * 16 + lr;
            if (r >= n) r = n - 1;
            a[mt] = *(const bf16x8*)(h1b + (size_t)r * 128 + ks * 32 + lk * 8);
        }
#pragma unroll
        for (int nt = 0; nt < 4; ++nt) {
            int g = half * 4 + nt;
            bf16x8 b = *(const bf16x8*)(Wf2 + (size_t)((g * 4 + ks) * 512 + l * 8));
            acc[0][nt] = MFMA16(a[0], b, acc[0][nt], 0, 0, 0);
            acc[1][nt] = MFMA16(a[1], b, acc[1][nt], 0, 0, 0);
        }
    }
#pragma unroll
    for (int nt = 0; nt < 4; ++nt) {
        int g = half * 4 + nt;
        int mat = g >> 1;
        int c = (g * 16 + lr) & 31;
        const float* bp = (mat == 0) ? bq : (mat == 1) ? bk : (mat == 2) ? bv : bs;
        float bias = bp[c];
#pragma unroll
        for (int mt = 0; mt < 2; ++mt)
#pragma unroll
            for (int i = 0; i < 4; ++i)
                lds[w][mt * 16 + lk * 4 + i][nt * 16 + lr] = f2bf(acc[mt][nt][i] + bias);
    }
    unsigned short* outA = (half == 0) ? qs2 : kv2 + 32; // q : v
    unsigned short* outB = (half == 0) ? kv2 : qs2 + 32; // k : s
    int rl8 = l >> 3, ci = (l & 7) * 4;
#pragma unroll
    for (int p = 0; p < 4; ++p) {
        int rl = p * 8 + rl8;
        int r = rb + rl;
        if (r < n) {
            uint2 va = *(const uint2*)&lds[w][rl][ci];
            *(uint2*)(outA + (size_t)r * 64 + ci) = va;
            uint2 vb = *(const uint2*)&lds[w][rl][32 + ci];
            *(uint2*)(outB + (size_t)r * 64 + ci) = vb;
        }
    }
}

// ---------------- Layer-1 attention aggregate ----------------
// one wave per dst node; lane = slot(0-3)*16 + w(0-15); lane owns channels [w*8, w*8+8).
// 8 edges per iteration; ONE dwordx4 gather per edge-lane (k in .xy, v in .zw).
// Dot/acc on f32x2 packed math (v_pk_fma_f32).

__global__ __launch_bounds__(256) void k_agg1(
    const unsigned short* __restrict__ qs1, const unsigned char* __restrict__ kv8,
    const int* __restrict__ row, const int* __restrict__ boff,
    const int* __restrict__ col, uint4* __restrict__ h1b, int n)
{
    int i = blockIdx.x * 4 + (threadIdx.x >> 6);
    if (i >= n) return;
    int lane = threadIdx.x & 63;
    int slot = lane >> 4, w = lane & 15;
    f32x2 q2[4];
    {
        uint4 qu = *(const uint4*)(qs1 + (size_t)i * 256 + w * 8);
        q2[0] = bfp2(qu.x); q2[1] = bfp2(qu.y); q2[2] = bfp2(qu.z); q2[3] = bfp2(qu.w);
    }
    f32x2 acc2[4] = {};
    float d = 0.f;
    int s = row[i] + boff[i >> 10];
    int e = row[i + 1] + boff[(i + 1) >> 10];
    for (int t = s; t < e; t += 8) {
        int ta = t + slot, tb = t + 4 + slot;
        bool va = ta < e, vb = tb < e;
        int ja = col[va ? ta : s];
        int jb = col[vb ? tb : s];
        uint4 A = *(const uint4*)(kv8 + (size_t)ja * 256 + w * 16);
        uint4 B = *(const uint4*)(kv8 + (size_t)jb * 256 + w * 16);
        f32x2 pa = CVT8(A.x, false) * q2[0];
        pa += CVT8(A.x, true)  * q2[1];
        pa += CVT8(A.y, false) * q2[2];
        pa += CVT8(A.y, true)  * q2[3];
        f32x2 pb = CVT8(B.x, false) * q2[0];
        pb += CVT8(B.x, true)  * q2[1];
        pb += CVT8(B.y, false) * q2[2];
        pb += CVT8(B.y, true)  * q2[3];
        float la = pa[0] + pa[1];
        float lb = pb[0] + pb[1];
        la += __shfl_xor(la, 1);  lb += __shfl_xor(lb, 1);
        la += __shfl_xor(la, 2);  lb += __shfl_xor(lb, 2);
        float wa = va ? __expf(la * SCALE) : 0.f;
        float wb = vb ? __expf(lb * SCALE) : 0.f;
        d += wa + wb;
        f32x2 wa2 = (f32x2){wa, wa};
        f32x2 wb2 = (f32x2){wb, wb};
        acc2[0] += wa2 * CVT8(A.z, false);
        acc2[1] += wa2 * CVT8(A.z, true);
        acc2[2] += wa2 * CVT8(A.w, false);
        acc2[3] += wa2 * CVT8(A.w, true);
        acc2[0] += wb2 * CVT8(B.z, false);
        acc2[1] += wb2 * CVT8(B.z, true);
        acc2[2] += wb2 * CVT8(B.w, false);
        acc2[3] += wb2 * CVT8(B.w, true);
    }
    float acc[8] = {acc2[0][0], acc2[0][1], acc2[1][0], acc2[1][1],
                    acc2[2][0], acc2[2][1], acc2[3][0], acc2[3][1]};
#pragma unroll
    for (int m = 16; m <= 32; m <<= 1) {
        d += __shfl_xor(d, m);
#pragma unroll
        for (int c = 0; c < 8; ++c) acc[c] += __shfl_xor(acc[c], m);
    }
    if (slot == 0) {
        float inv = (d > 0.f) ? 1.f / d : 0.f;
        uint4 su = *(const uint4*)(qs1 + (size_t)i * 256 + 128 + w * 8);
        f32x2 sv[4] = {bfp2(su.x), bfp2(su.y), bfp2(su.z), bfp2(su.w)};
        unsigned o[4];
#pragma unroll
        for (int p = 0; p < 4; ++p) {
            float rx = acc[2 * p] * inv + sv[p][0];
            float ry = acc[2 * p + 1] * inv + sv[p][1];
            rx = (rx > 0.f) ? rx : expm1f(rx); // ELU
            ry = (ry > 0.f) ? ry : expm1f(ry);
            o[p] = ((unsigned)f2bf(ry) << 16) | (unsigned)f2bf(rx);
        }
        h1b[(size_t)i * 16 + w] = make_uint4(o[0], o[1], o[2], o[3]);
    }
}

// ---------------- Layer-2 attention aggregate ----------------
// one wave per dst node; lane = slot(0-15)*4 + qr(0-3); 16 edges/iteration.
// Packed f32x2 math.

__global__ __launch_bounds__(256) void k_agg2(
    const unsigned short* __restrict__ qs2, const unsigned short* __restrict__ kv2,
    const int* __restrict__ row, const int* __restrict__ boff,
    const int* __restrict__ col, float* __restrict__ out, int n)
{
    int i = blockIdx.x * 4 + (threadIdx.x >> 6);
    if (i >= n) return;
    int lane = threadIdx.x & 63;
    int slot = lane >> 2, qr = lane & 3;
    f32x2 q2[4];
    {
        uint4 qu = *(const uint4*)(qs2 + (size_t)i * 64 + qr * 8);
        q2[0] = bfp2(qu.x); q2[1] = bfp2(qu.y); q2[2] = bfp2(qu.z); q2[3] = bfp2(qu.w);
    }
    f32x2 acc2[4] = {};
    float d = 0.f;
    int s = row[i] + boff[i >> 10];
    int e = row[i + 1] + boff[(i + 1) >> 10];
    for (int t = s; t < e; t += 16) {
        int te = t + slot;
        bool va = te < e;
        int j = col[va ? te : s];
        const unsigned short* p = kv2 + (size_t)j * 64;
        uint4 ku = *(const uint4*)(p + qr * 8);
        uint4 vu = *(const uint4*)(p + 32 + qr * 8);
        f32x2 pp = bfp2(ku.x) * q2[0];
        pp += bfp2(ku.y) * q2[1];
        pp += bfp2(ku.z) * q2[2];
        pp += bfp2(ku.w) * q2[3];
        float lg = pp[0] + pp[1];
        lg += __shfl_xor(lg, 1);
        lg += __shfl_xor(lg, 2);
        float wv = va ? __expf(lg * SCALE) : 0.f;
        d += wv;
        f32x2 w2 = (f32x2){wv, wv};
        acc2[0] += w2 * bfp2(vu.x);
        acc2[1] += w2 * bfp2(vu.y);
        acc2[2] += w2 * bfp2(vu.z);
        acc2[3] += w2 * bfp2(vu.w);
    }
    float acc[8] = {acc2[0][0], acc2[0][1], acc2[1][0], acc2[1][1],
                    acc2[2][0], acc2[2][1], acc2[3][0], acc2[3][1]};
#pragma unroll
    for (int m = 4; m <= 32; m <<= 1) {
        d += __shfl_xor(d, m);
#pragma unroll
        for (int c = 0; c < 8; ++c) acc[c] += __shfl_xor(acc[c], m);
    }
    if (slot == 0) {
        float inv = (d > 0.f) ? 1.f / d : 0.f;
        uint4 su = *(const uint4*)(qs2 + (size_t)i * 64 + 32 + qr * 8);
        f32x2 sv[4] = {bfp2(su.x), bfp2(su.y), bfp2(su.z), bfp2(su.w)};
        float4 o0, o1;
        o0.x = acc[0] * inv + sv[0][0];
        o0.y = acc[1] * inv + sv[0][1];
        o0.z = acc[2] * inv + sv[1][0];
        o0.w = acc[3] * inv + sv[1][1];
        o1.x = acc[4] * inv + sv[2][0];
        o1.y = acc[5] * inv + sv[2][1];
        o1.z = acc[6] * inv + sv[3][0];
        o1.w = acc[7] * inv + sv[3][1];
        *(float4*)&out[(size_t)i * 32 + qr * 8] = o0;
        *(float4*)&out[(size_t)i * 32 + qr * 8 + 4] = o1;
    }
}

// ---------------- launch ----------------

extern "C" void kernel_launch(void* const* d_in, const int* in_sizes, int n_in,
                              void* d_out, int out_size, void* d_ws, size_t ws_size,
                              hipStream_t stream)
{
    const int N = N_NODES, E = N_EDGES;
    const float* x   = (const float*)d_in[0];
    const int* edge  = (const int*)d_in[1];
    const int* src   = edge;       // edge_index[0]
    const int* dst   = edge + E;   // edge_index[1]
    const float* Wq1 = (const float*)d_in[2];  const float* bq1 = (const float*)d_in[3];
    const float* Wk1 = (const float*)d_in[4];  const float* bk1 = (const float*)d_in[5];
    const float* Wv1 = (const float*)d_in[6];  const float* bv1 = (const float*)d_in[7];
    const float* Ws1 = (const float*)d_in[8];  const float* bs1 = (const float*)d_in[9];
    const float* Wq2 = (const float*)d_in[10]; const float* bq2 = (const float*)d_in[11];
    const float* Wk2 = (const float*)d_in[12]; const float* bk2 = (const float*)d_in[13];
    const float* Wv2 = (const float*)d_in[14]; const float* bv2 = (const float*)d_in[15];
    const float* Ws2 = (const float*)d_in[16]; const float* bs2 = (const float*)d_in[17];

    char* ws = (char*)d_ws;
    size_t off = 0;
    auto alloc = [&](size_t bytes) -> void* {
        void* p = ws + off;
        off += (bytes + 255) & ~(size_t)255;
        return p;
    };
    unsigned short* qs1 = (unsigned short*)alloc((size_t)N * 256 * 2); // 25.6 MB
    unsigned char*  kv8 = (unsigned char*)alloc((size_t)N * 256);      // 12.8 MB (k,v interleaved fp8)
    unsigned short* h1b = (unsigned short*)alloc((size_t)N * 128 * 2); // 12.8 MB
    unsigned short* qs2 = (unsigned short*)alloc((size_t)N * 64 * 2);  //  6.4 MB
    unsigned short* kv2 = (unsigned short*)alloc((size_t)N * 64 * 2);  //  6.4 MB
    unsigned short* Wf1 = (unsigned short*)alloc(32768 * 2);
    unsigned short* Wf2 = (unsigned short*)alloc(16384 * 2);
    int* row_ptr  = (int*)alloc((size_t)(N + 1) * 4);
    int* cnt      = (int*)alloc((size_t)(N + 64) * 4); // cnt[N] + ctr
    int* ctr      = cnt + N;
    int* rank     = (int*)alloc((size_t)E * 4);
    int* colb     = (int*)alloc((size_t)E * 4);
    int* bsum     = (int*)alloc(64 * 4);
    int* boff     = (int*)alloc(64 * 4);

    hipMemsetAsync(cnt, 0, (size_t)(N + 64) * 4, stream);
    k_ph<<<HB + 192, 256, 0, stream>>>(dst, cnt, rank,
                                       Wq1, Wk1, Wv1, Ws1, Wq2, Wk2, Wv2, Ws2,
                                       Wf1, Wf2);
    k_gs<<<GB1 + NBS, 256, 0, stream>>>(cnt, row_ptr, bsum, boff, ctr,
                                        x, Wf1, bq1, bk1, bv1, bs1, qs1, kv8, N);
    k_scat<<<HB, 256, 0, stream>>>(src, dst, row_ptr, boff, rank, colb);
    k_agg1<<<(N + 3) / 4, 256, 0, stream>>>(qs1, kv8, row_ptr, boff, colb, (uint4*)h1b, N);
    k_gemm2m<<<(N + 63) / 64, 256, 0, stream>>>(h1b, Wf2, bq2, bk2, bv2, bs2, qs2, kv2, N);
    k_agg2<<<(N + 3) / 4, 256, 0, stream>>>(qs2, kv2, row_ptr, boff, colb, (float*)d_out, N);
}